// Round 1
// baseline (326.862 us; speedup 1.0000x reference)
//
#include <hip/hip_runtime.h>

// SVSAlgorithm: per-pixel sequential threshold recurrence over T frames,
// fused with 3x3 constant-kernel "DiffErosion" conv + relu epilogue.
//
// Design:
//  - tile 16x16 threads = 14x14 interior outputs + 1-pixel halo (halo pixels
//    recompute their own recurrence; conv done from an LDS tile).
//  - T split into NCHUNK chunks; each block redundantly runs the cheap
//    state-only recurrence (no exp / no store) up to its chunk start. x fits
//    in L3 (167.8MB < 256MB) so warm-up re-reads are cache-served.
//  - conv == box-sum since all 9 kernel weights are equal; zero padding of
//    (1-hot) is equivalent to hot=1 outside the image.
//  - state updates replicate reference f32 op order exactly (bit-exact chain);
//    sigmoid uses __expf (only smooth effect on output).

#define TILE_W 16
#define TILE_H 16
#define IN_W 14
#define IN_H 14
#define NCHUNK 8
#define BUF 8

constexpr int T_FRAMES = 2048;
constexpr int H_IMG = 128;
constexpr int W_IMG = 160;
constexpr int HW = H_IMG * W_IMG;
constexpr int CHUNK = T_FRAMES / NCHUNK; // 256

__global__ __launch_bounds__(256)
void svs_fused(const float* __restrict__ x, const float* __restrict__ params,
               const float* __restrict__ HT0, const float* __restrict__ LT0,
               const float* __restrict__ kern, float* __restrict__ out)
{
    const int tx = threadIdx.x & 15;
    const int ty = threadIdx.x >> 4;
    const int gx = (int)blockIdx.x * IN_W + tx - 1;
    const int gy = (int)blockIdx.y * IN_H + ty - 1;
    // dispatch longest warm-up (largest chunk index) first
    const int chunk = (NCHUNK - 1) - (int)blockIdx.z;

    const bool valid = (gx >= 0) & (gx < W_IMG) & (gy >= 0) & (gy < H_IMG);
    const int cx = min(max(gx, 0), W_IMG - 1);
    const int cy = min(max(gy, 0), H_IMG - 1);
    const int pix = cy * W_IMG + cx;

    const float dC   = params[0];
    const float dO   = params[1];
    const float dHot = params[2];
    const float kw   = kern[4];   // all 9 weights equal (2/9)

    float HT = valid ? HT0[pix] : 0.0f;
    float LT = valid ? LT0[pix] : 0.0f;

    const float* xp = x + pix;
    const int t0 = chunk * CHUNK;

    // ---- warm-up: state-only recurrence for t in [0, t0) ----
    for (int t = 0; t < t0; t += BUF) {
        float v[BUF];
        #pragma unroll
        for (int i = 0; i < BUF; ++i) v[i] = xp[(t + i) * HW];
        #pragma unroll
        for (int i = 0; i < BUF; ++i) {
            const float img = v[i];
            HT += ((img - HT) > 0.0f) ? dO : -dC;
            LT += ((LT - img) > 0.0f) ? -dO : dC;
        }
    }

    __shared__ float sm[BUF][TILE_H][TILE_W + 1];

    const bool doOut = (tx >= 1) & (tx <= IN_W) & (ty >= 1) & (ty <= IN_H) & valid;
    float* op = out + pix;

    for (int tb = t0; tb < t0 + CHUNK; tb += BUF) {
        float v[BUF];
        #pragma unroll
        for (int i = 0; i < BUF; ++i) v[i] = xp[(tb + i) * HW];
        #pragma unroll
        for (int i = 0; i < BUF; ++i) {
            const float img = v[i];
            const float aH = img - HT;
            const float zH = (aH - dHot) * 500.0f;
            const float hotH = 1.0f / (1.0f + __expf(-zH));
            HT += (aH > 0.0f) ? dO : -dC;
            const float aL = LT - img;
            const float zL = (aL - dHot) * 500.0f;
            const float hotL = 1.0f / (1.0f + __expf(-zL));
            LT += (aL > 0.0f) ? -dO : dC;
            sm[i][ty][tx] = valid ? (hotH + hotL) : 1.0f;
        }
        __syncthreads();
        if (doOut) {
            #pragma unroll
            for (int i = 0; i < BUF; ++i) {
                float S = 0.0f;
                #pragma unroll
                for (int dy = -1; dy <= 1; ++dy) {
                    S += sm[i][ty + dy][tx - 1];
                    S += sm[i][ty + dy][tx    ];
                    S += sm[i][ty + dy][tx + 1];
                }
                const float sub = kw * (9.0f - S);
                const float o = 1.0f - sub;
                op[(tb + i) * HW] = (o > 0.0f) ? o : 0.0f;
            }
        }
        __syncthreads();
    }
}

extern "C" void kernel_launch(void* const* d_in, const int* in_sizes, int n_in,
                              void* d_out, int out_size, void* d_ws, size_t ws_size,
                              hipStream_t stream) {
    const float* x      = (const float*)d_in[0];
    const float* params = (const float*)d_in[1];
    const float* HT0p   = (const float*)d_in[2];
    const float* LT0p   = (const float*)d_in[3];
    const float* kern   = (const float*)d_in[4];
    float* out = (float*)d_out;

    dim3 grid((W_IMG + IN_W - 1) / IN_W,   // 12
              (H_IMG + IN_H - 1) / IN_H,   // 10
              NCHUNK);                     // 8
    svs_fused<<<grid, dim3(256), 0, stream>>>(x, params, HT0p, LT0p, kern, out);
}

// Round 2
// 285.455 us; speedup vs baseline: 1.1451x; 1.1451x over previous
//
#include <hip/hip_runtime.h>

// SVSAlgorithm: per-pixel sequential threshold recurrence over T frames,
// fused with 3x3 constant-kernel "DiffErosion" conv + relu epilogue.
//
// Two-launch design:
//  L1 svs_scan: 1 thread/pixel, full-T state-only scan, snapshots (HT,LT)
//     every SNAP frames into d_ws. Reads x exactly once. Deep double-buffered
//     prefetch (2x16 in flight) to ride out HBM latency at low occupancy.
//  L2 svs_compute: 16x16 tile (14x14 interior + halo recompute), one block per
//     (tile, 128-frame slice). Loads snapshot, runs full compute (sigmoid via
//     __expf, conv == box-sum since all 9 weights equal, relu), nontemporal
//     stores. Uniform work, 1920 blocks -> high occupancy, no tail.
//  State update replicates reference f32 op order exactly (sub/cmp/add);
//  only the sigmoid (smooth) uses fast math.

#define TILE_W 16
#define TILE_H 16
#define IN_W 14
#define IN_H 14
#define BUF 8        // frames per LDS stage in compute pass
#define PRE 16       // prefetch half-depth in scan pass

constexpr int T_FRAMES = 2048;
constexpr int H_IMG = 128;
constexpr int W_IMG = 160;
constexpr int HW = H_IMG * W_IMG;
constexpr int SNAP = 128;                       // snapshot period
constexpr int NSNAP = T_FRAMES / SNAP - 1;      // 15 snapshots (t=128..1920)
constexpr size_t WS_NEEDED = (size_t)NSNAP * HW * sizeof(float2);

// ---------------- L1: state-only scan, snapshots every SNAP frames ---------
__global__ __launch_bounds__(256)
void svs_scan(const float* __restrict__ x, const float* __restrict__ params,
              const float* __restrict__ HT0, const float* __restrict__ LT0,
              float2* __restrict__ snap)
{
    const int pix = (int)blockIdx.x * 256 + (int)threadIdx.x;  // 80 blocks cover HW
    const float dC = params[0];
    const float dO = params[1];

    float HT = HT0[pix];
    float LT = LT0[pix];
    const float* xp = x + pix;

    float va[PRE], vb[PRE];
    #pragma unroll
    for (int i = 0; i < PRE; ++i) va[i] = xp[i * HW];

    for (int t = 0; t < T_FRAMES; t += 2 * PRE) {
        #pragma unroll
        for (int i = 0; i < PRE; ++i) vb[i] = xp[(t + PRE + i) * HW];
        #pragma unroll
        for (int i = 0; i < PRE; ++i) {
            const float img = va[i];
            HT += ((img - HT) > 0.0f) ? dO : -dC;
            LT += ((LT - img) > 0.0f) ? -dO : dC;
        }
        if (((t + PRE) & (SNAP - 1)) == 0) {
            const int k = (t + PRE) / SNAP;     // 1..16
            if (k <= NSNAP) snap[(k - 1) * HW + pix] = make_float2(HT, LT);
        }
        if (t + 2 * PRE < T_FRAMES) {
            #pragma unroll
            for (int i = 0; i < PRE; ++i) va[i] = xp[(t + 2 * PRE + i) * HW];
        }
        #pragma unroll
        for (int i = 0; i < PRE; ++i) {
            const float img = vb[i];
            HT += ((img - HT) > 0.0f) ? dO : -dC;
            LT += ((LT - img) > 0.0f) ? -dO : dC;
        }
        if (((t + 2 * PRE) & (SNAP - 1)) == 0) {
            const int k = (t + 2 * PRE) / SNAP;
            if (k <= NSNAP) snap[(k - 1) * HW + pix] = make_float2(HT, LT);
        }
    }
}

// ---------------- L2: per-slice fused compute -----------------------------
__global__ __launch_bounds__(256)
void svs_compute(const float* __restrict__ x, const float* __restrict__ params,
                 const float* __restrict__ HT0, const float* __restrict__ LT0,
                 const float* __restrict__ kern, const float2* __restrict__ snap,
                 float* __restrict__ out)
{
    const int tx = threadIdx.x & 15;
    const int ty = threadIdx.x >> 4;
    const int gx = (int)blockIdx.x * IN_W + tx - 1;
    const int gy = (int)blockIdx.y * IN_H + ty - 1;
    const int slice = (int)blockIdx.z;
    const int t0 = slice * SNAP;

    const bool valid = (gx >= 0) & (gx < W_IMG) & (gy >= 0) & (gy < H_IMG);
    const int cx = min(max(gx, 0), W_IMG - 1);
    const int cy = min(max(gy, 0), H_IMG - 1);
    const int pix = cy * W_IMG + cx;

    const float dC   = params[0];
    const float dO   = params[1];
    const float dHot = params[2];
    const float kw   = kern[4];   // all 9 weights equal (2/9)

    float HT, LT;
    if (slice == 0) {
        HT = valid ? HT0[pix] : 0.0f;
        LT = valid ? LT0[pix] : 0.0f;
    } else {
        const float2 s = snap[(slice - 1) * HW + pix];
        HT = valid ? s.x : 0.0f;
        LT = valid ? s.y : 0.0f;
    }

    __shared__ float sm[BUF][TILE_H][TILE_W + 1];

    const bool doOut = (tx >= 1) & (tx <= IN_W) & (ty >= 1) & (ty <= IN_H) & valid;
    const float* xp = x + pix;
    float* op = out + pix;

    for (int tb = t0; tb < t0 + SNAP; tb += BUF) {
        float v[BUF];
        #pragma unroll
        for (int i = 0; i < BUF; ++i) v[i] = xp[(tb + i) * HW];
        #pragma unroll
        for (int i = 0; i < BUF; ++i) {
            const float img = v[i];
            const float aH = img - HT;
            const float zH = (aH - dHot) * 500.0f;
            const float hotH = 1.0f / (1.0f + __expf(-zH));
            HT += (aH > 0.0f) ? dO : -dC;
            const float aL = LT - img;
            const float zL = (aL - dHot) * 500.0f;
            const float hotL = 1.0f / (1.0f + __expf(-zL));
            LT += (aL > 0.0f) ? -dO : dC;
            sm[i][ty][tx] = valid ? (hotH + hotL) : 1.0f;
        }
        __syncthreads();
        if (doOut) {
            #pragma unroll
            for (int i = 0; i < BUF; ++i) {
                float S = 0.0f;
                #pragma unroll
                for (int dy = -1; dy <= 1; ++dy) {
                    S += sm[i][ty + dy][tx - 1];
                    S += sm[i][ty + dy][tx    ];
                    S += sm[i][ty + dy][tx + 1];
                }
                const float sub = kw * (9.0f - S);
                const float o = 1.0f - sub;
                __builtin_nontemporal_store((o > 0.0f) ? o : 0.0f, &op[(tb + i) * HW]);
            }
        }
        __syncthreads();
    }
}

// ---------------- Fallback: R1 fused kernel (if ws too small) -------------
#define NCHUNK 8
constexpr int CHUNK = T_FRAMES / NCHUNK;

__global__ __launch_bounds__(256)
void svs_fused(const float* __restrict__ x, const float* __restrict__ params,
               const float* __restrict__ HT0, const float* __restrict__ LT0,
               const float* __restrict__ kern, float* __restrict__ out)
{
    const int tx = threadIdx.x & 15;
    const int ty = threadIdx.x >> 4;
    const int gx = (int)blockIdx.x * IN_W + tx - 1;
    const int gy = (int)blockIdx.y * IN_H + ty - 1;
    const int chunk = (NCHUNK - 1) - (int)blockIdx.z;

    const bool valid = (gx >= 0) & (gx < W_IMG) & (gy >= 0) & (gy < H_IMG);
    const int cx = min(max(gx, 0), W_IMG - 1);
    const int cy = min(max(gy, 0), H_IMG - 1);
    const int pix = cy * W_IMG + cx;

    const float dC   = params[0];
    const float dO   = params[1];
    const float dHot = params[2];
    const float kw   = kern[4];

    float HT = valid ? HT0[pix] : 0.0f;
    float LT = valid ? LT0[pix] : 0.0f;

    const float* xp = x + pix;
    const int t0 = chunk * CHUNK;

    for (int t = 0; t < t0; t += BUF) {
        float v[BUF];
        #pragma unroll
        for (int i = 0; i < BUF; ++i) v[i] = xp[(t + i) * HW];
        #pragma unroll
        for (int i = 0; i < BUF; ++i) {
            const float img = v[i];
            HT += ((img - HT) > 0.0f) ? dO : -dC;
            LT += ((LT - img) > 0.0f) ? -dO : dC;
        }
    }

    __shared__ float sm[BUF][TILE_H][TILE_W + 1];
    const bool doOut = (tx >= 1) & (tx <= IN_W) & (ty >= 1) & (ty <= IN_H) & valid;
    float* op = out + pix;

    for (int tb = t0; tb < t0 + CHUNK; tb += BUF) {
        float v[BUF];
        #pragma unroll
        for (int i = 0; i < BUF; ++i) v[i] = xp[(tb + i) * HW];
        #pragma unroll
        for (int i = 0; i < BUF; ++i) {
            const float img = v[i];
            const float aH = img - HT;
            const float zH = (aH - dHot) * 500.0f;
            const float hotH = 1.0f / (1.0f + __expf(-zH));
            HT += (aH > 0.0f) ? dO : -dC;
            const float aL = LT - img;
            const float zL = (aL - dHot) * 500.0f;
            const float hotL = 1.0f / (1.0f + __expf(-zL));
            LT += (aL > 0.0f) ? -dO : dC;
            sm[i][ty][tx] = valid ? (hotH + hotL) : 1.0f;
        }
        __syncthreads();
        if (doOut) {
            #pragma unroll
            for (int i = 0; i < BUF; ++i) {
                float S = 0.0f;
                #pragma unroll
                for (int dy = -1; dy <= 1; ++dy) {
                    S += sm[i][ty + dy][tx - 1];
                    S += sm[i][ty + dy][tx    ];
                    S += sm[i][ty + dy][tx + 1];
                }
                const float sub = kw * (9.0f - S);
                const float o = 1.0f - sub;
                op[(tb + i) * HW] = (o > 0.0f) ? o : 0.0f;
            }
        }
        __syncthreads();
    }
}

extern "C" void kernel_launch(void* const* d_in, const int* in_sizes, int n_in,
                              void* d_out, int out_size, void* d_ws, size_t ws_size,
                              hipStream_t stream) {
    const float* x      = (const float*)d_in[0];
    const float* params = (const float*)d_in[1];
    const float* HT0p   = (const float*)d_in[2];
    const float* LT0p   = (const float*)d_in[3];
    const float* kern   = (const float*)d_in[4];
    float* out = (float*)d_out;

    if (ws_size >= WS_NEEDED) {
        float2* snap = (float2*)d_ws;
        svs_scan<<<dim3(HW / 256), dim3(256), 0, stream>>>(x, params, HT0p, LT0p, snap);
        dim3 grid2((W_IMG + IN_W - 1) / IN_W,   // 12
                   (H_IMG + IN_H - 1) / IN_H,   // 10
                   T_FRAMES / SNAP);            // 16
        svs_compute<<<grid2, dim3(256), 0, stream>>>(x, params, HT0p, LT0p, kern, snap, out);
    } else {
        dim3 grid((W_IMG + IN_W - 1) / IN_W, (H_IMG + IN_H - 1) / IN_H, NCHUNK);
        svs_fused<<<grid, dim3(256), 0, stream>>>(x, params, HT0p, LT0p, kern, out);
    }
}

// Round 3
// 161.915 us; speedup vs baseline: 2.0187x; 1.7630x over previous
//
#include <hip/hip_runtime.h>

// SVSAlgorithm: per-pixel sequential threshold recurrence over T frames,
// fused with 3x3 constant-kernel "DiffErosion" conv + relu epilogue.
//
// Two-launch design:
//  L1 svs_scan: 1 thread/pixel, full-T state-only scan, snapshots (HT,LT)
//     every SNAP frames into d_ws. Reads x exactly once. 32-deep prefetch
//     (in-flight ~2.6MB device-wide ~ BW*latency), 320 one-wave blocks.
//  L2 svs_compute: 16x16 tile (14x14 interior + halo recompute), one block
//     per (tile, 128-frame slice). Sigmoid via exp2(fma)+v_rcp (state-update
//     comparisons/adds remain bit-identical to reference). Conv = box-sum
//     (all 9 weights equal): vertical via 2 LDS reads + own reg, horizontal
//     via DPP row_shr/row_shl (rows are 16-lane groups). XCD-grouped block
//     remap so adjacent-bx tiles share an XCD L2 and their partial 128B
//     output lines merge before writeback.

#define TILE_W 16
#define TILE_H 16
#define IN_W 14
#define IN_H 14
#define BUF 8        // frames per LDS stage in compute pass
#define PRE 32       // prefetch depth (scan pass)

constexpr int T_FRAMES = 2048;
constexpr int H_IMG = 128;
constexpr int W_IMG = 160;
constexpr int HW = H_IMG * W_IMG;
constexpr int SNAP = 128;                       // snapshot period
constexpr int NSNAP = T_FRAMES / SNAP - 1;      // 15 snapshots (t=128..1920)
constexpr size_t WS_NEEDED = (size_t)NSNAP * HW * sizeof(float2);
constexpr float C1 = 721.3475204444817f;        // 500 * log2(e)

__device__ __forceinline__ float dpp_from_left(float v) {   // lane n <- lane n-1 (16-lane rows)
    return __int_as_float(__builtin_amdgcn_update_dpp(0, __float_as_int(v), 0x111, 0xF, 0xF, true));
}
__device__ __forceinline__ float dpp_from_right(float v) {  // lane n <- lane n+1
    return __int_as_float(__builtin_amdgcn_update_dpp(0, __float_as_int(v), 0x101, 0xF, 0xF, true));
}

// ---------------- L1: state-only scan, snapshots every SNAP frames ---------
__global__ __launch_bounds__(64)
void svs_scan(const float* __restrict__ x, const float* __restrict__ params,
              const float* __restrict__ HT0, const float* __restrict__ LT0,
              float2* __restrict__ snap)
{
    const int pix = (int)blockIdx.x * 64 + (int)threadIdx.x;  // 320 blocks cover HW
    const float dC = params[0];
    const float dO = params[1];

    float HT = HT0[pix];
    float LT = LT0[pix];
    const float* xp = x + pix;

    float va[PRE], vb[PRE];
    #pragma unroll
    for (int i = 0; i < PRE; ++i) va[i] = xp[i * HW];

    for (int t = 0; t < T_FRAMES; t += 2 * PRE) {
        #pragma unroll
        for (int i = 0; i < PRE; ++i) vb[i] = xp[(t + PRE + i) * HW];
        #pragma unroll
        for (int i = 0; i < PRE; ++i) {
            const float img = va[i];
            HT = ((img - HT) > 0.0f) ? (HT + dO) : (HT - dC);
            LT = ((LT - img) > 0.0f) ? (LT - dO) : (LT + dC);
        }
        if (((t + PRE) & (SNAP - 1)) == 0) {
            const int k = (t + PRE) / SNAP;
            if (k <= NSNAP) snap[(k - 1) * HW + pix] = make_float2(HT, LT);
        }
        if (t + 2 * PRE < T_FRAMES) {
            #pragma unroll
            for (int i = 0; i < PRE; ++i) va[i] = xp[(t + 2 * PRE + i) * HW];
        }
        #pragma unroll
        for (int i = 0; i < PRE; ++i) {
            const float img = vb[i];
            HT = ((img - HT) > 0.0f) ? (HT + dO) : (HT - dC);
            LT = ((LT - img) > 0.0f) ? (LT - dO) : (LT + dC);
        }
        if (((t + 2 * PRE) & (SNAP - 1)) == 0) {
            const int k = (t + 2 * PRE) / SNAP;
            if (k <= NSNAP) snap[(k - 1) * HW + pix] = make_float2(HT, LT);
        }
    }
}

// ---------------- L2: per-slice fused compute -----------------------------
__global__ __launch_bounds__(256)
void svs_compute(const float* __restrict__ x, const float* __restrict__ params,
                 const float* __restrict__ HT0, const float* __restrict__ LT0,
                 const float* __restrict__ kern, const float2* __restrict__ snap,
                 float* __restrict__ out)
{
    // XCD-grouped remap: contiguous chunks of linear block id per XCD so
    // adjacent-bx tiles (which share output cache lines) land on one XCD L2.
    const int lin = (int)blockIdx.x + 12 * (int)blockIdx.y + 120 * (int)blockIdx.z;
    const int w   = (lin & 7) * 240 + (lin >> 3);        // 1920 % 8 == 0 -> bijective
    const int bx  = w % 12;
    const int by  = (w / 12) % 10;
    const int slice = w / 120;

    const int tx = threadIdx.x & 15;
    const int ty = threadIdx.x >> 4;
    const int gx = bx * IN_W + tx - 1;
    const int gy = by * IN_H + ty - 1;
    const int t0 = slice * SNAP;

    const bool valid = (gx >= 0) & (gx < W_IMG) & (gy >= 0) & (gy < H_IMG);
    const int cx = min(max(gx, 0), W_IMG - 1);
    const int cy = min(max(gy, 0), H_IMG - 1);
    const int pix = cy * W_IMG + cx;

    const float dC   = params[0];
    const float dO   = params[1];
    const float dHot = params[2];
    const float kw   = kern[4];        // all 9 weights equal (2/9)
    const float c0   = dHot * C1;      // exp2 arg = fma(a, -C1, c0)

    float HT, LT;
    if (slice == 0) {
        HT = valid ? HT0[pix] : 0.0f;
        LT = valid ? LT0[pix] : 0.0f;
    } else {
        const float2 s = snap[(slice - 1) * HW + pix];
        HT = valid ? s.x : 0.0f;
        LT = valid ? s.y : 0.0f;
    }

    __shared__ float sm[BUF][TILE_H][TILE_W + 1];

    const bool doOut = (tx >= 1) & (tx <= IN_W) & (ty >= 1) & (ty <= IN_H) & valid;
    const int ym = max(ty - 1, 0);
    const int yp = min(ty + 1, TILE_H - 1);
    const float* xp = x + pix;
    float* op = out + pix;

    for (int tb = t0; tb < t0 + SNAP; tb += BUF) {
        float v[BUF], hot[BUF];
        #pragma unroll
        for (int i = 0; i < BUF; ++i) v[i] = xp[(tb + i) * HW];
        #pragma unroll
        for (int i = 0; i < BUF; ++i) {
            const float img = v[i];
            const float aH = img - HT;
            const float eH = __builtin_amdgcn_exp2f(fmaf(aH, -C1, c0));
            const float hH = __builtin_amdgcn_rcpf(1.0f + eH);
            HT = (aH > 0.0f) ? (HT + dO) : (HT - dC);
            const float aL = LT - img;
            const float eL = __builtin_amdgcn_exp2f(fmaf(aL, -C1, c0));
            const float hL = __builtin_amdgcn_rcpf(1.0f + eL);
            LT = (aL > 0.0f) ? (LT - dO) : (LT + dC);
            hot[i] = valid ? (hH + hL) : 1.0f;
            sm[i][ty][tx] = hot[i];
        }
        __syncthreads();
        #pragma unroll
        for (int i = 0; i < BUF; ++i) {
            const float r0 = sm[i][ym][tx];
            const float r1 = sm[i][yp][tx];
            const float vs = r0 + hot[i] + r1;               // vertical box sum
            const float S  = vs + dpp_from_left(vs) + dpp_from_right(vs);
            float o = fmaf(S, kw, -1.0f);                    // 1 - kw*(9-S) = kw*S - 1
            o = fmaxf(o, 0.0f);
            if (doOut) op[(tb + i) * HW] = o;
        }
        __syncthreads();
    }
}

// ---------------- Fallback: R1 fused kernel (if ws too small) -------------
#define NCHUNK 8
constexpr int CHUNK = T_FRAMES / NCHUNK;

__global__ __launch_bounds__(256)
void svs_fused(const float* __restrict__ x, const float* __restrict__ params,
               const float* __restrict__ HT0, const float* __restrict__ LT0,
               const float* __restrict__ kern, float* __restrict__ out)
{
    const int tx = threadIdx.x & 15;
    const int ty = threadIdx.x >> 4;
    const int gx = (int)blockIdx.x * IN_W + tx - 1;
    const int gy = (int)blockIdx.y * IN_H + ty - 1;
    const int chunk = (NCHUNK - 1) - (int)blockIdx.z;

    const bool valid = (gx >= 0) & (gx < W_IMG) & (gy >= 0) & (gy < H_IMG);
    const int cx = min(max(gx, 0), W_IMG - 1);
    const int cy = min(max(gy, 0), H_IMG - 1);
    const int pix = cy * W_IMG + cx;

    const float dC   = params[0];
    const float dO   = params[1];
    const float dHot = params[2];
    const float kw   = kern[4];

    float HT = valid ? HT0[pix] : 0.0f;
    float LT = valid ? LT0[pix] : 0.0f;

    const float* xp = x + pix;
    const int t0 = chunk * CHUNK;

    for (int t = 0; t < t0; t += BUF) {
        float v[BUF];
        #pragma unroll
        for (int i = 0; i < BUF; ++i) v[i] = xp[(t + i) * HW];
        #pragma unroll
        for (int i = 0; i < BUF; ++i) {
            const float img = v[i];
            HT = ((img - HT) > 0.0f) ? (HT + dO) : (HT - dC);
            LT = ((LT - img) > 0.0f) ? (LT - dO) : (LT + dC);
        }
    }

    __shared__ float sm[BUF][TILE_H][TILE_W + 1];
    const bool doOut = (tx >= 1) & (tx <= IN_W) & (ty >= 1) & (ty <= IN_H) & valid;
    const int ym = max(ty - 1, 0);
    const int yp = min(ty + 1, TILE_H - 1);
    const float c0 = dHot * C1;
    float* op = out + pix;

    for (int tb = t0; tb < t0 + CHUNK; tb += BUF) {
        float v[BUF], hot[BUF];
        #pragma unroll
        for (int i = 0; i < BUF; ++i) v[i] = xp[(tb + i) * HW];
        #pragma unroll
        for (int i = 0; i < BUF; ++i) {
            const float img = v[i];
            const float aH = img - HT;
            const float eH = __builtin_amdgcn_exp2f(fmaf(aH, -C1, c0));
            const float hH = __builtin_amdgcn_rcpf(1.0f + eH);
            HT = (aH > 0.0f) ? (HT + dO) : (HT - dC);
            const float aL = LT - img;
            const float eL = __builtin_amdgcn_exp2f(fmaf(aL, -C1, c0));
            const float hL = __builtin_amdgcn_rcpf(1.0f + eL);
            LT = (aL > 0.0f) ? (LT - dO) : (LT + dC);
            hot[i] = valid ? (hH + hL) : 1.0f;
            sm[i][ty][tx] = hot[i];
        }
        __syncthreads();
        #pragma unroll
        for (int i = 0; i < BUF; ++i) {
            const float r0 = sm[i][ym][tx];
            const float r1 = sm[i][yp][tx];
            const float vs = r0 + hot[i] + r1;
            const float S  = vs + dpp_from_left(vs) + dpp_from_right(vs);
            float o = fmaf(S, kw, -1.0f);
            o = fmaxf(o, 0.0f);
            if (doOut) op[(tb + i) * HW] = o;
        }
        __syncthreads();
    }
}

extern "C" void kernel_launch(void* const* d_in, const int* in_sizes, int n_in,
                              void* d_out, int out_size, void* d_ws, size_t ws_size,
                              hipStream_t stream) {
    const float* x      = (const float*)d_in[0];
    const float* params = (const float*)d_in[1];
    const float* HT0p   = (const float*)d_in[2];
    const float* LT0p   = (const float*)d_in[3];
    const float* kern   = (const float*)d_in[4];
    float* out = (float*)d_out;

    if (ws_size >= WS_NEEDED) {
        float2* snap = (float2*)d_ws;
        svs_scan<<<dim3(HW / 64), dim3(64), 0, stream>>>(x, params, HT0p, LT0p, snap);
        dim3 grid2((W_IMG + IN_W - 1) / IN_W,   // 12
                   (H_IMG + IN_H - 1) / IN_H,   // 10
                   T_FRAMES / SNAP);            // 16
        svs_compute<<<grid2, dim3(256), 0, stream>>>(x, params, HT0p, LT0p, kern, snap, out);
    } else {
        dim3 grid((W_IMG + IN_W - 1) / IN_W, (H_IMG + IN_H - 1) / IN_H, NCHUNK);
        svs_fused<<<grid, dim3(256), 0, stream>>>(x, params, HT0p, LT0p, kern, out);
    }
}